// Round 13
// baseline (168.157 us; speedup 1.0000x reference)
//
#include <hip/hip_runtime.h>
#include <hip/hip_bf16.h>
#include <stdint.h>

typedef __hip_bfloat16 bf16;
typedef __attribute__((ext_vector_type(8))) short bf16x8;
typedef __attribute__((ext_vector_type(4))) float f32x4;
typedef __attribute__((ext_vector_type(16))) float f32x16;

#define MFMA16(a,b,c) __builtin_amdgcn_mfma_f32_16x16x32_bf16((a),(b),(c),0,0,0)
#define MFMA32(a,b,c) __builtin_amdgcn_mfma_f32_32x32x16_bf16((a),(b),(c),0,0,0)

#define B_ 2
#define T_ 2048
#define E_ 1024
#define H_ 16
#define D_ 64
#define M_ (B_*T_)   // 4096
#define PROJ_ELEMS (32ull * 2048ull * 64ull)   // 4.19M elems per Q/K/V tensor

__device__ __forceinline__ void gload_lds16(const bf16* g, bf16* l) {
  __builtin_amdgcn_global_load_lds(
      (const __attribute__((address_space(1))) unsigned int*)g,
      (__attribute__((address_space(3))) unsigned int*)l,
      16, 0, 0);
}

// ---------------- pre-pass: f32 -> bf16 convert ----------------
__global__ __launch_bounds__(256) void cvt_x_kernel(const float* __restrict__ in,
                                                    bf16* __restrict__ out) {
  int i = blockIdx.x * 256 + threadIdx.x;        // each thread: 4 floats
  float4 v = reinterpret_cast<const float4*>(in)[i];
  union { bf16 h[4]; unsigned long long u; } t;
  t.h[0] = __float2bfloat16(v.x);
  t.h[1] = __float2bfloat16(v.y);
  t.h[2] = __float2bfloat16(v.z);
  t.h[3] = __float2bfloat16(v.w);
  reinterpret_cast<unsigned long long*>(out)[i] = t.u;
}

// ---------------- pre-pass: 4x W [K][N] f32 -> Wt [N][K] bf16 (fused) ----------------
__global__ __launch_bounds__(256) void transpose_cvt4_kernel(
    const float* __restrict__ W0, const float* __restrict__ W1,
    const float* __restrict__ W2, const float* __restrict__ W3,
    bf16* __restrict__ T0, bf16* __restrict__ T1,
    bf16* __restrict__ T2, bf16* __restrict__ T3) {
  __shared__ float tile[32][33];
  const float* W; bf16* Wt;
  switch (blockIdx.z) {
    case 0: W = W0; Wt = T0; break;
    case 1: W = W1; Wt = T1; break;
    case 2: W = W2; Wt = T2; break;
    default: W = W3; Wt = T3; break;
  }
  const int tx = threadIdx.x, ty = threadIdx.y;  // 32 x 8
  const int n0 = blockIdx.x * 32, k0 = blockIdx.y * 32;
#pragma unroll
  for (int i = 0; i < 4; i++)
    tile[ty + 8*i][tx] = W[(size_t)(k0 + ty + 8*i) * E_ + n0 + tx];
  __syncthreads();
#pragma unroll
  for (int i = 0; i < 4; i++)
    Wt[(size_t)(n0 + ty + 8*i) * E_ + k0 + tx] = __float2bfloat16(tile[tx][ty + 8*i]);
}

// ---------------- GEMM: C[M][N] = A[M][K] * Bt[N][K]^T ----------------
// mode 2: write f32 + bias to row-major [M][E]  (final output)
// mode 3: cols [0,1024)->Q bf16 [BH][T][D] *scale, [1024,2048)->K (N=2048 grid)
// mode 4: A=WvT -> C[dg][token]; store V^T bf16 at b*2^21 + dg*2048 + t
//         (coalesced: consecutive lanes = consecutive t)
__global__ __launch_bounds__(256) void gemm_bt_kernel(
    const bf16* __restrict__ A, const bf16* __restrict__ Bt,
    void* __restrict__ out, const float* __restrict__ bias,
    const int mode, const float scale)
{
  constexpr int K = E_;
  __shared__ __align__(16) bf16 As[128*32];
  __shared__ __align__(16) bf16 Bs[128*32];
  const int tid = threadIdx.x;
  const int w = tid >> 6, l = tid & 63;
  const int lc = l & 15, lr = l >> 4;
  const int m0 = blockIdx.y * 128, n0 = blockIdx.x * 128;
  const int wr = (w >> 1) * 64, wc = (w & 1) * 64;

  f32x4 acc[4][4];
#pragma unroll
  for (int m = 0; m < 4; m++)
#pragma unroll
    for (int n = 0; n < 4; n++) acc[m][n] = (f32x4)0.0f;

  const int srow = l >> 2;            // 0..15
  const int scol = (l & 3) * 8;       // k element offset

  for (int k0 = 0; k0 < K; k0 += 32) {
#pragma unroll
    for (int p = 0; p < 2; p++) {
      const int r = (w*2 + p) * 16 + srow;
      gload_lds16(A  + (size_t)(m0 + r) * K + k0 + scol, &As[(w*2 + p) * 512]);
      gload_lds16(Bt + (size_t)(n0 + r) * K + k0 + scol, &Bs[(w*2 + p) * 512]);
    }
    __syncthreads();
    bf16x8 af[4], bfr[4];
#pragma unroll
    for (int m = 0; m < 4; m++)
      af[m] = *reinterpret_cast<const bf16x8*>(&As[(wr + m*16 + lc) * 32 + lr * 8]);
#pragma unroll
    for (int n = 0; n < 4; n++)
      bfr[n] = *reinterpret_cast<const bf16x8*>(&Bs[(wc + n*16 + lc) * 32 + lr * 8]);
#pragma unroll
    for (int m = 0; m < 4; m++)
#pragma unroll
      for (int n = 0; n < 4; n++)
        acc[m][n] = MFMA16(af[m], bfr[n], acc[m][n]);
    __syncthreads();
  }

  const int proj = blockIdx.x >> 3;   // uniform per block (mode 3: 0=Q, 1=K)
#pragma unroll
  for (int m = 0; m < 4; m++) {
#pragma unroll
    for (int n = 0; n < 4; n++) {
#pragma unroll
      for (int j = 0; j < 4; j++) {
        const int row = m0 + wr + m*16 + lr*4 + j;
        const int col = n0 + wc + n*16 + lc;
        if (mode == 2) {
          reinterpret_cast<float*>(out)[(size_t)row * E_ + col] = acc[m][n][j] + bias[col];
        } else if (mode == 4) {
          // row = dg (h*64+d), col = token (b*2048+t); contiguous in t
          reinterpret_cast<bf16*>(out)[(size_t)(col >> 11) * ((size_t)H_ * D_ * T_)
                                       + (size_t)row * T_ + (col & (T_-1))]
              = __float2bfloat16(acc[m][n][j]);
        } else {
          const int cp = col & (E_-1);
          const int b = row >> 11, t = row & (T_-1);
          const int h = cp >> 6,  d = cp & (D_-1);
          const float v = acc[m][n][j] * (proj == 0 ? scale : 1.0f);
          const size_t idx = (((size_t)(b*H_ + h)) * T_ + t) * D_ + d;  // Q, K row-major
          reinterpret_cast<bf16*>(out)[proj * PROJ_ELEMS + idx] = __float2bfloat16(v);
        }
      }
    }
  }
}

// ---------------- flash attention (causal), swapped-QK^T, static-shift softmax ----------------
// (unchanged from r12: 74 us plateau; VALU cut confirmed, latency-bound)
__global__ __launch_bounds__(128, 2) void attn_fwd_kernel(
    const bf16* __restrict__ Q, const bf16* __restrict__ Kt,
    const bf16* __restrict__ Vt, bf16* __restrict__ O)
{
  __shared__ float Lo[64 * 33];      // warp1 partial O^T [d][q], stride 33
  __shared__ float Ll[32];           // warp1 partial psum per q-col

  const int tid = threadIdx.x;
  const int w = tid >> 6, l = tid & 63;
  const int ln = l & 31;
  const int hi = l >> 5;
  const int bid = blockIdx.x;
  const int bh  = (bid & 7) * 4 + ((bid >> 3) & 3);   // XCD-pinned, 4 heads/XCD
  const int qt  = 63 - (bid >> 5);   // 0..63, heaviest first (LPT)
  const int q0  = qt * 32;

  const bf16* Qb = Q + (size_t)bh * T_ * D_;
  const bf16* kp = Kt + (size_t)bh * T_ * D_ + (size_t)(w*32 + ln) * D_ + hi*8;
  const bf16* vp = Vt + (size_t)bh * D_ * T_ + (size_t)ln * T_ + w*32 + hi*8;

  bf16x8 qf[4];
#pragma unroll
  for (int s = 0; s < 4; s++)
    qf[s] = *reinterpret_cast<const bf16x8*>(
        &Qb[(size_t)(q0 + ln) * D_ + s*16 + hi*8]);

  f32x16 oacc0 = (f32x16)0.0f, oacc1 = (f32x16)0.0f;
  float psum = 0.0f;

  union U4 { uint32_t u[4]; bf16x8 v; };

  for (int kt = w; kt <= qt; kt += 2) {
    bf16x8 kf[4];
#pragma unroll
    for (int s = 0; s < 4; s++)
      kf[s] = *reinterpret_cast<const bf16x8*>(kp + s*16);

    f32x16 sT = (f32x16)0.0f;
#pragma unroll
    for (int s = 0; s < 4; s++) sT = MFMA32(kf[s], qf[s], sT);

    if (kt == qt) {
#pragma unroll
      for (int r = 0; r < 16; r++) {
        const int mm = (r&3) + 8*(r>>2) + 4*hi;
        if (mm > ln) sT[r] = -1e30f;
      }
    }

    float pe[16];
#pragma unroll
    for (int r = 0; r < 16; r++) {
      const float x = sT[r] - 8.0f;
      asm("v_exp_f32 %0, %1" : "=v"(pe[r]) : "v"(x));
    }
    {
      const float t0 = (pe[0]+pe[1]) + (pe[2]+pe[3]);
      const float t1 = (pe[4]+pe[5]) + (pe[6]+pe[7]);
      const float t2 = (pe[8]+pe[9]) + (pe[10]+pe[11]);
      const float t3 = (pe[12]+pe[13]) + (pe[14]+pe[15]);
      psum += (t0+t1) + (t2+t3);
    }

    uint32_t u_[8];
#pragma unroll
    for (int i = 0; i < 8; i++)
      asm("v_cvt_pk_bf16_f32 %0, %1, %2"
          : "=v"(u_[i]) : "v"(pe[2*i]), "v"(pe[2*i+1]));
    const uint32_t x0 = __shfl_xor(hi ? u_[0] : u_[2], 32);
    const uint32_t x1 = __shfl_xor(hi ? u_[1] : u_[3], 32);
    const uint32_t x2 = __shfl_xor(hi ? u_[4] : u_[6], 32);
    const uint32_t x3 = __shfl_xor(hi ? u_[5] : u_[7], 32);
    U4 pf0, pf1;
    pf0.u[0] = hi ? x0 : u_[0];  pf0.u[1] = hi ? x1 : u_[1];
    pf0.u[2] = hi ? u_[2] : x0;  pf0.u[3] = hi ? u_[3] : x1;
    pf1.u[0] = hi ? x2 : u_[4];  pf1.u[1] = hi ? x3 : u_[5];
    pf1.u[2] = hi ? u_[6] : x2;  pf1.u[3] = hi ? u_[7] : x3;

    bf16x8 vf00 = *reinterpret_cast<const bf16x8*>(vp);
    bf16x8 vf01 = *reinterpret_cast<const bf16x8*>(vp + 16);
    bf16x8 vf10 = *reinterpret_cast<const bf16x8*>(vp + (size_t)32*T_);
    bf16x8 vf11 = *reinterpret_cast<const bf16x8*>(vp + (size_t)32*T_ + 16);
    oacc0 = MFMA32(vf00, pf0.v, oacc0);
    oacc0 = MFMA32(vf01, pf1.v, oacc0);
    oacc1 = MFMA32(vf10, pf0.v, oacc1);
    oacc1 = MFMA32(vf11, pf1.v, oacc1);

    kp += (size_t)64 * D_;
    vp += 64;
  }

  psum += __shfl_xor(psum, 32);

  if (w == 1) {
    if (hi == 0) Ll[ln] = psum;
#pragma unroll
    for (int r = 0; r < 16; r++) {
      const int d = (r&3) + 8*(r>>2) + 4*hi;
      Lo[d * 33 + ln] = oacc0[r];
      Lo[(32 + d) * 33 + ln] = oacc1[r];
    }
  }
  __syncthreads();

  if (w == 0) {
    const float inv = 1.0f / (psum + Ll[ln]);
    const int b = bh >> 4, hh = bh & 15;
    const size_t rowbase = (size_t)(b * T_ + q0 + ln) * E_ + hh * 64;
#pragma unroll
    for (int r = 0; r < 16; r++) {
      const int d = (r&3) + 8*(r>>2) + 4*hi;
      O[rowbase + d]      = __float2bfloat16((oacc0[r] + Lo[d*33 + ln]) * inv);
      O[rowbase + 32 + d] = __float2bfloat16((oacc1[r] + Lo[(32+d)*33 + ln]) * inv);
    }
  }
}

// ---------------- launch ----------------
extern "C" void kernel_launch(void* const* d_in, const int* in_sizes, int n_in,
                              void* d_out, int out_size, void* d_ws, size_t ws_size,
                              hipStream_t stream) {
  const float* x  = (const float*)d_in[0];
  const float* Wq = (const float*)d_in[1];
  const float* Wk = (const float*)d_in[2];
  const float* Wv = (const float*)d_in[3];
  const float* Wo = (const float*)d_in[4];
  const float* bo = (const float*)d_in[5];
  float* out = (float*)d_out;

  char* ws = (char*)d_ws;
  bf16* xb  = (bf16*)(ws);                         // 8 MB  [4096][1024]
  bf16* WqT = (bf16*)(ws + (8ull  << 20));         // 2 MB  [N][K]  (Wq|Wk contiguous)
  bf16* WkT = (bf16*)(ws + (10ull << 20));
  bf16* WvT = (bf16*)(ws + (12ull << 20));
  bf16* WoT = (bf16*)(ws + (14ull << 20));
  bf16* Qb  = (bf16*)(ws + (16ull << 20));         // 8 MB [BH][T][D]; K, V^T follow
  bf16* Ob  = (bf16*)(ws + (40ull << 20));         // 8 MB  [4096][1024]

  cvt_x_kernel<<<4096, 256, 0, stream>>>(x, xb);
  transpose_cvt4_kernel<<<dim3(32, 32, 4), dim3(32, 8), 0, stream>>>(
      Wq, Wk, Wv, Wo, WqT, WkT, WvT, WoT);

  // Q,K projection: N = 2048, Bt = [WqT|WkT] contiguous
  const float qscale = 0.125f * 1.44269504f;       // D^-0.5 * log2(e)
  gemm_bt_kernel<<<dim3(16, 32), 256, 0, stream>>>(xb, WqT, Qb, nullptr, 3, qscale);
  // V^T projection: C[dg][token] = WvT * xb^T, coalesced V^T stores (mode 4)
  gemm_bt_kernel<<<dim3(32, 8), 256, 0, stream>>>(WvT, xb, Qb + 2*PROJ_ELEMS,
                                                  nullptr, 4, 1.0f);

  attn_fwd_kernel<<<2048, 128, 0, stream>>>(
      Qb, Qb + PROJ_ELEMS, Qb + 2*PROJ_ELEMS, Ob);

  gemm_bt_kernel<<<dim3(8, 32), 256, 0, stream>>>(Ob, WoT, out, bo, 2, 1.0f);
}

// Round 14
// 156.547 us; speedup vs baseline: 1.0742x; 1.0742x over previous
//
#include <hip/hip_runtime.h>
#include <hip/hip_bf16.h>
#include <stdint.h>

typedef __hip_bfloat16 bf16;
typedef __attribute__((ext_vector_type(8))) short bf16x8;
typedef __attribute__((ext_vector_type(4))) float f32x4;
typedef __attribute__((ext_vector_type(16))) float f32x16;

#define MFMA16(a,b,c) __builtin_amdgcn_mfma_f32_16x16x32_bf16((a),(b),(c),0,0,0)
#define MFMA32(a,b,c) __builtin_amdgcn_mfma_f32_32x32x16_bf16((a),(b),(c),0,0,0)

#define B_ 2
#define T_ 2048
#define E_ 1024
#define H_ 16
#define D_ 64
#define M_ (B_*T_)   // 4096
#define PROJ_ELEMS (32ull * 2048ull * 64ull)   // 4.19M elems per Q/K/V tensor

__device__ __forceinline__ void gload_lds16(const bf16* g, bf16* l) {
  __builtin_amdgcn_global_load_lds(
      (const __attribute__((address_space(1))) unsigned int*)g,
      (__attribute__((address_space(3))) unsigned int*)l,
      16, 0, 0);
}

// ---------------- pre-pass: f32 -> bf16 convert ----------------
__global__ __launch_bounds__(256) void cvt_x_kernel(const float* __restrict__ in,
                                                    bf16* __restrict__ out) {
  int i = blockIdx.x * 256 + threadIdx.x;        // each thread: 4 floats
  float4 v = reinterpret_cast<const float4*>(in)[i];
  union { bf16 h[4]; unsigned long long u; } t;
  t.h[0] = __float2bfloat16(v.x);
  t.h[1] = __float2bfloat16(v.y);
  t.h[2] = __float2bfloat16(v.z);
  t.h[3] = __float2bfloat16(v.w);
  reinterpret_cast<unsigned long long*>(out)[i] = t.u;
}

// ---------------- pre-pass: 4x W [K][N] f32 -> Wt [N][K] bf16 (fused) ----------------
__global__ __launch_bounds__(256) void transpose_cvt4_kernel(
    const float* __restrict__ W0, const float* __restrict__ W1,
    const float* __restrict__ W2, const float* __restrict__ W3,
    bf16* __restrict__ T0, bf16* __restrict__ T1,
    bf16* __restrict__ T2, bf16* __restrict__ T3) {
  __shared__ float tile[32][33];
  const float* W; bf16* Wt;
  switch (blockIdx.z) {
    case 0: W = W0; Wt = T0; break;
    case 1: W = W1; Wt = T1; break;
    case 2: W = W2; Wt = T2; break;
    default: W = W3; Wt = T3; break;
  }
  const int tx = threadIdx.x, ty = threadIdx.y;  // 32 x 8
  const int n0 = blockIdx.x * 32, k0 = blockIdx.y * 32;
#pragma unroll
  for (int i = 0; i < 4; i++)
    tile[ty + 8*i][tx] = W[(size_t)(k0 + ty + 8*i) * E_ + n0 + tx];
  __syncthreads();
#pragma unroll
  for (int i = 0; i < 4; i++)
    Wt[(size_t)(n0 + ty + 8*i) * E_ + k0 + tx] = __float2bfloat16(tile[tx][ty + 8*i]);
}

// ---------------- GEMM: C[M][N] = A[M][K] * Bt[N][K]^T, 64x128 tile ----------------
// r13 diagnosis: 128x128 tiles -> 256-512 block grids = 1-2 blocks/CU; GEMM
// section ran at ~400 TF avg (occupancy-starved). 64x128 tile doubles the grid:
// 4 waves in 2x2, each 32x64 (acc[2][4]); LDS 12 KB -> 4+ blocks/CU resident.
// mode 2: write f32 + bias to row-major [M][E]  (final output)
// mode 3: cols [0,1024)->Q bf16 [BH][T][D] *scale, [1024,2048)->K
// mode 4: A=WvT -> C[dg][token]; store V^T bf16 (coalesced in t)
__global__ __launch_bounds__(256) void gemm_bt_kernel(
    const bf16* __restrict__ A, const bf16* __restrict__ Bt,
    void* __restrict__ out, const float* __restrict__ bias,
    const int mode, const float scale)
{
  constexpr int K = E_;
  __shared__ __align__(16) bf16 As[64*32];    // 4 KB
  __shared__ __align__(16) bf16 Bs[128*32];   // 8 KB
  const int tid = threadIdx.x;
  const int w = tid >> 6, l = tid & 63;
  const int lc = l & 15, lr = l >> 4;
  const int m0 = blockIdx.y * 64, n0 = blockIdx.x * 128;
  const int wr = (w >> 1) * 32, wc = (w & 1) * 64;

  f32x4 acc[2][4];
#pragma unroll
  for (int m = 0; m < 2; m++)
#pragma unroll
    for (int n = 0; n < 4; n++) acc[m][n] = (f32x4)0.0f;

  const int srow = l >> 2;            // 0..15
  const int scol = (l & 3) * 8;       // k element offset

  for (int k0 = 0; k0 < K; k0 += 32) {
    // A: 64 rows, 1 wave-load each
    gload_lds16(A + (size_t)(m0 + w*16 + srow) * K + k0 + scol, &As[w * 512]);
    // B: 128 rows, 2 wave-loads each
#pragma unroll
    for (int p = 0; p < 2; p++) {
      const int r = (w*2 + p) * 16 + srow;
      gload_lds16(Bt + (size_t)(n0 + r) * K + k0 + scol, &Bs[(w*2 + p) * 512]);
    }
    __syncthreads();
    bf16x8 af[2], bfr[4];
#pragma unroll
    for (int m = 0; m < 2; m++)
      af[m] = *reinterpret_cast<const bf16x8*>(&As[(wr + m*16 + lc) * 32 + lr * 8]);
#pragma unroll
    for (int n = 0; n < 4; n++)
      bfr[n] = *reinterpret_cast<const bf16x8*>(&Bs[(wc + n*16 + lc) * 32 + lr * 8]);
#pragma unroll
    for (int m = 0; m < 2; m++)
#pragma unroll
      for (int n = 0; n < 4; n++)
        acc[m][n] = MFMA16(af[m], bfr[n], acc[m][n]);
    __syncthreads();
  }

  const int proj = blockIdx.x >> 3;   // uniform per block (mode 3: 0=Q, 1=K)
#pragma unroll
  for (int m = 0; m < 2; m++) {
#pragma unroll
    for (int n = 0; n < 4; n++) {
#pragma unroll
      for (int j = 0; j < 4; j++) {
        const int row = m0 + wr + m*16 + lr*4 + j;
        const int col = n0 + wc + n*16 + lc;
        if (mode == 2) {
          reinterpret_cast<float*>(out)[(size_t)row * E_ + col] = acc[m][n][j] + bias[col];
        } else if (mode == 4) {
          // row = dg (h*64+d), col = token (b*2048+t); contiguous in t
          reinterpret_cast<bf16*>(out)[(size_t)(col >> 11) * ((size_t)H_ * D_ * T_)
                                       + (size_t)row * T_ + (col & (T_-1))]
              = __float2bfloat16(acc[m][n][j]);
        } else {
          const int cp = col & (E_-1);
          const int b = row >> 11, t = row & (T_-1);
          const int h = cp >> 6,  d = cp & (D_-1);
          const float v = acc[m][n][j] * (proj == 0 ? scale : 1.0f);
          const size_t idx = (((size_t)(b*H_ + h)) * T_ + t) * D_ + d;  // Q, K row-major
          reinterpret_cast<bf16*>(out)[proj * PROJ_ELEMS + idx] = __float2bfloat16(v);
        }
      }
    }
  }
}

// ---------------- flash attention (causal), swapped-QK^T, static-shift softmax ----------------
// (unchanged from r12: 74 us plateau)
__global__ __launch_bounds__(128, 2) void attn_fwd_kernel(
    const bf16* __restrict__ Q, const bf16* __restrict__ Kt,
    const bf16* __restrict__ Vt, bf16* __restrict__ O)
{
  __shared__ float Lo[64 * 33];      // warp1 partial O^T [d][q], stride 33
  __shared__ float Ll[32];           // warp1 partial psum per q-col

  const int tid = threadIdx.x;
  const int w = tid >> 6, l = tid & 63;
  const int ln = l & 31;
  const int hi = l >> 5;
  const int bid = blockIdx.x;
  const int bh  = (bid & 7) * 4 + ((bid >> 3) & 3);   // XCD-pinned, 4 heads/XCD
  const int qt  = 63 - (bid >> 5);   // 0..63, heaviest first (LPT)
  const int q0  = qt * 32;

  const bf16* Qb = Q + (size_t)bh * T_ * D_;
  const bf16* kp = Kt + (size_t)bh * T_ * D_ + (size_t)(w*32 + ln) * D_ + hi*8;
  const bf16* vp = Vt + (size_t)bh * D_ * T_ + (size_t)ln * T_ + w*32 + hi*8;

  bf16x8 qf[4];
#pragma unroll
  for (int s = 0; s < 4; s++)
    qf[s] = *reinterpret_cast<const bf16x8*>(
        &Qb[(size_t)(q0 + ln) * D_ + s*16 + hi*8]);

  f32x16 oacc0 = (f32x16)0.0f, oacc1 = (f32x16)0.0f;
  float psum = 0.0f;

  union U4 { uint32_t u[4]; bf16x8 v; };

  for (int kt = w; kt <= qt; kt += 2) {
    bf16x8 kf[4];
#pragma unroll
    for (int s = 0; s < 4; s++)
      kf[s] = *reinterpret_cast<const bf16x8*>(kp + s*16);

    f32x16 sT = (f32x16)0.0f;
#pragma unroll
    for (int s = 0; s < 4; s++) sT = MFMA32(kf[s], qf[s], sT);

    if (kt == qt) {
#pragma unroll
      for (int r = 0; r < 16; r++) {
        const int mm = (r&3) + 8*(r>>2) + 4*hi;
        if (mm > ln) sT[r] = -1e30f;
      }
    }

    float pe[16];
#pragma unroll
    for (int r = 0; r < 16; r++) {
      const float x = sT[r] - 8.0f;
      asm("v_exp_f32 %0, %1" : "=v"(pe[r]) : "v"(x));
    }
    {
      const float t0 = (pe[0]+pe[1]) + (pe[2]+pe[3]);
      const float t1 = (pe[4]+pe[5]) + (pe[6]+pe[7]);
      const float t2 = (pe[8]+pe[9]) + (pe[10]+pe[11]);
      const float t3 = (pe[12]+pe[13]) + (pe[14]+pe[15]);
      psum += (t0+t1) + (t2+t3);
    }

    uint32_t u_[8];
#pragma unroll
    for (int i = 0; i < 8; i++)
      asm("v_cvt_pk_bf16_f32 %0, %1, %2"
          : "=v"(u_[i]) : "v"(pe[2*i]), "v"(pe[2*i+1]));
    const uint32_t x0 = __shfl_xor(hi ? u_[0] : u_[2], 32);
    const uint32_t x1 = __shfl_xor(hi ? u_[1] : u_[3], 32);
    const uint32_t x2 = __shfl_xor(hi ? u_[4] : u_[6], 32);
    const uint32_t x3 = __shfl_xor(hi ? u_[5] : u_[7], 32);
    U4 pf0, pf1;
    pf0.u[0] = hi ? x0 : u_[0];  pf0.u[1] = hi ? x1 : u_[1];
    pf0.u[2] = hi ? u_[2] : x0;  pf0.u[3] = hi ? u_[3] : x1;
    pf1.u[0] = hi ? x2 : u_[4];  pf1.u[1] = hi ? x3 : u_[5];
    pf1.u[2] = hi ? u_[6] : x2;  pf1.u[3] = hi ? u_[7] : x3;

    bf16x8 vf00 = *reinterpret_cast<const bf16x8*>(vp);
    bf16x8 vf01 = *reinterpret_cast<const bf16x8*>(vp + 16);
    bf16x8 vf10 = *reinterpret_cast<const bf16x8*>(vp + (size_t)32*T_);
    bf16x8 vf11 = *reinterpret_cast<const bf16x8*>(vp + (size_t)32*T_ + 16);
    oacc0 = MFMA32(vf00, pf0.v, oacc0);
    oacc0 = MFMA32(vf01, pf1.v, oacc0);
    oacc1 = MFMA32(vf10, pf0.v, oacc1);
    oacc1 = MFMA32(vf11, pf1.v, oacc1);

    kp += (size_t)64 * D_;
    vp += 64;
  }

  psum += __shfl_xor(psum, 32);

  if (w == 1) {
    if (hi == 0) Ll[ln] = psum;
#pragma unroll
    for (int r = 0; r < 16; r++) {
      const int d = (r&3) + 8*(r>>2) + 4*hi;
      Lo[d * 33 + ln] = oacc0[r];
      Lo[(32 + d) * 33 + ln] = oacc1[r];
    }
  }
  __syncthreads();

  if (w == 0) {
    const float inv = 1.0f / (psum + Ll[ln]);
    const int b = bh >> 4, hh = bh & 15;
    const size_t rowbase = (size_t)(b * T_ + q0 + ln) * E_ + hh * 64;
#pragma unroll
    for (int r = 0; r < 16; r++) {
      const int d = (r&3) + 8*(r>>2) + 4*hi;
      O[rowbase + d]      = __float2bfloat16((oacc0[r] + Lo[d*33 + ln]) * inv);
      O[rowbase + 32 + d] = __float2bfloat16((oacc1[r] + Lo[(32+d)*33 + ln]) * inv);
    }
  }
}

// ---------------- launch ----------------
extern "C" void kernel_launch(void* const* d_in, const int* in_sizes, int n_in,
                              void* d_out, int out_size, void* d_ws, size_t ws_size,
                              hipStream_t stream) {
  const float* x  = (const float*)d_in[0];
  const float* Wq = (const float*)d_in[1];
  const float* Wk = (const float*)d_in[2];
  const float* Wv = (const float*)d_in[3];
  const float* Wo = (const float*)d_in[4];
  const float* bo = (const float*)d_in[5];
  float* out = (float*)d_out;

  char* ws = (char*)d_ws;
  bf16* xb  = (bf16*)(ws);                         // 8 MB  [4096][1024]
  bf16* WqT = (bf16*)(ws + (8ull  << 20));         // 2 MB  [N][K]  (Wq|Wk contiguous)
  bf16* WkT = (bf16*)(ws + (10ull << 20));
  bf16* WvT = (bf16*)(ws + (12ull << 20));
  bf16* WoT = (bf16*)(ws + (14ull << 20));
  bf16* Qb  = (bf16*)(ws + (16ull << 20));         // 8 MB [BH][T][D]; K, V^T follow
  bf16* Ob  = (bf16*)(ws + (40ull << 20));         // 8 MB  [4096][1024]

  cvt_x_kernel<<<4096, 256, 0, stream>>>(x, xb);
  transpose_cvt4_kernel<<<dim3(32, 32, 4), dim3(32, 8), 0, stream>>>(
      Wq, Wk, Wv, Wo, WqT, WkT, WvT, WoT);

  // Q,K projection: N = 2048, Bt = [WqT|WkT] contiguous; grid 1024 blocks
  const float qscale = 0.125f * 1.44269504f;       // D^-0.5 * log2(e)
  gemm_bt_kernel<<<dim3(16, 64), 256, 0, stream>>>(xb, WqT, Qb, nullptr, 3, qscale);
  // V^T projection: C[dg][token] = WvT * xb^T (mode 4); grid 512 blocks
  gemm_bt_kernel<<<dim3(32, 16), 256, 0, stream>>>(WvT, xb, Qb + 2*PROJ_ELEMS,
                                                   nullptr, 4, 1.0f);

  attn_fwd_kernel<<<2048, 128, 0, stream>>>(
      Qb, Qb + PROJ_ELEMS, Qb + 2*PROJ_ELEMS, Ob);

  // output projection: grid 512 blocks
  gemm_bt_kernel<<<dim3(8, 64), 256, 0, stream>>>(Ob, WoT, out, bo, 2, 1.0f);
}